// Round 11
// baseline (120.706 us; speedup 1.0000x reference)
//
#include <hip/hip_runtime.h>
#include <hip/hip_bf16.h>
#include <stdint.h>

// Problem constants (from reference setup_inputs)
#define L_DIM 2048
#define B_DIM 32
#define E_DIM 512
#define HID_DIM 512
#define M_DIM (L_DIM * B_DIM)   // 65536 rows, row m = l*32 + b

typedef float f32x4 __attribute__((ext_vector_type(4)));
typedef short bf16x8 __attribute__((ext_vector_type(8)));

// ws layout (bytes); requires ws_size >= 3211264 (~3.1 MB) — unchanged (known OK)
#define OFF_BASE  0         // 32*512 f32          = 65536
#define OFF_WT    65536     // 512*512 bf16        = 524288  -> 589824
#define OFF_LOGIT 589824    // 65536 f32           = 262144  -> 851968
#define OFF_P     851968    // 65536 f32           = 262144  -> 1114112
#define OFF_PART  1114112   // 32*32*512 f32       = 2097152 -> 3211264

__device__ __forceinline__ unsigned short f2bf(float f) {
  unsigned int u = __float_as_uint(f);
  u = (u + 0x7FFFu + ((u >> 16) & 1u)) >> 16;   // RNE
  return (unsigned short)u;
}

__device__ __forceinline__ float tanh_fast(float x) {
  float xc = fminf(fmaxf(x, -15.f), 15.f);
  float e = __expf(2.f * xc);
  return (e - 1.f) * __builtin_amdgcn_rcpf(e + 1.f);
}

// async global->LDS DMA, 16 B per lane (m97-verified path)
#define GLOAD_LDS16(gsrc, ldst) \
  __builtin_amdgcn_global_load_lds( \
      (const __attribute__((address_space(1))) void*)(gsrc), \
      (__attribute__((address_space(3))) void*)(ldst), 16, 0, 0)

// ---------------- kernel 1: base[b][h] = hidden[b]@W1_h + b1 ----------------
__global__ __launch_bounds__(256) void k_base(const float* __restrict__ hidden,
                                              const float* __restrict__ W1,
                                              const float* __restrict__ b1,
                                              float* __restrict__ base) {
  const int b = blockIdx.x;
  const int tid = threadIdx.x;
  __shared__ float hs[HID_DIM];
  {
    float2 v = *(const float2*)(hidden + (size_t)b * 512 + tid * 2);
    hs[tid * 2] = v.x; hs[tid * 2 + 1] = v.y;
  }
  __syncthreads();
  const int h = tid * 2;
  float2 b1v = *(const float2*)(b1 + h);
  float ax = b1v.x, ay = b1v.y;
#pragma unroll 8
  for (int e = 0; e < 512; ++e) {
    float2 w = *(const float2*)(W1 + (size_t)e * 512 + h);
    float hv = hs[e];
    ax = fmaf(hv, w.x, ax);
    ay = fmaf(hv, w.y, ay);
  }
  float2 r; r.x = ax; r.y = ay;
  *(float2*)(base + (size_t)b * 512 + h) = r;
}

// ------- kernel 2: pre-permute W1_e into MFMA-fragment order ------
// Wt unit index (16B units, 2048 per kc): u = (n>>7)*512 + ((n>>4)&7)*64 + lg*16 + (n&15)
// content: 8 bf16 of W1_e[k = kc*32 + lg*8 + j][n]
__global__ __launch_bounds__(256) void k_prep_wt(const float* __restrict__ W1,
                                                 unsigned short* __restrict__ Wt) {
  const int kc = blockIdx.x;   // 16 blocks
  const int tid = threadIdx.x;
  __shared__ unsigned short sh[32][516];   // +4 pad to spread strided col reads
#pragma unroll
  for (int i = 0; i < 16; ++i) {
    int f4 = i * 256 + tid;                 // 4096 float4 total
    int r = f4 >> 7;                        // 0..31
    int c = (f4 & 127) * 4;                 // 0..508
    float4 v = *(const float4*)(W1 + (size_t)(512 + kc * 32 + r) * 512 + c);
    sh[r][c + 0] = f2bf(v.x); sh[r][c + 1] = f2bf(v.y);
    sh[r][c + 2] = f2bf(v.z); sh[r][c + 3] = f2bf(v.w);
  }
  __syncthreads();
#pragma unroll
  for (int i = 0; i < 8; ++i) {
    int u = i * 256 + tid;                  // 0..2047
    int n = ((u >> 9) << 7) + (((u >> 6) & 7) << 4) + (u & 15);
    int k0 = ((u >> 4) & 3) << 3;
    alignas(16) unsigned short tmp[8];
#pragma unroll
    for (int j = 0; j < 8; ++j) tmp[j] = sh[k0 + j][n];
    *(uint4*)(Wt + ((size_t)kc * 2048 + u) * 8) = *(const uint4*)tmp;
  }
}

// ------- kernel 3: fused GEMM + tanh + W2 reduce -> logit[m] ---------------
// m97-structure transplant. BM=64, 512 thr = 8 waves, wave = 64x64 N-slice,
// acc[4][4]=64. B staged per-kc via global_load_lds width-16 into 32 KB LDS
// (double-buffered, linear DMA; Wt already fragment-ordered so frag ds_reads
// are lane-linear, 0 conflicts). x reg-staged (fp32->bf16) into 4 KB dbuf.
// ONE barrier per kc; compiler's vmcnt/lgkm drain before it is the known
// m97 stall, covered by 2 blocks/CU (72 KB LDS, <=128 regs via (512,4)).
__global__ __launch_bounds__(512, 4) void k_logits(
    const float* __restrict__ x, const unsigned short* __restrict__ Wt,
    const float* __restrict__ base, const float* __restrict__ W2,
    float* __restrict__ logit) {
  __shared__ unsigned short bs[2][16384];   // B tile: 2048 units x 16B (32 KB/buf)
  __shared__ unsigned short xsh[2][2048];   // x tile: 256 units x 16B (4 KB/buf)
  const int tid = threadIdx.x;
  const int m0 = blockIdx.x * 64;
  const int w = tid >> 6, lane = tid & 63;  // w = N-slice 0..7 (cols w*64..+63)
  const int lg = lane >> 4, l15 = lane & 15;

  // x staging map: row r = tid>>3 (0..63), seg = tid&7 (4 floats each)
  const int xr = tid >> 3, xseg = tid & 7;
  const float* xsrc = x + (size_t)(m0 + xr) * 512 + xseg * 4;
  const int xu8 = (((xr >> 4) << 6) + ((xseg >> 1) << 4) + (xr & 15)) * 8 +
                  (xseg & 1) * 4;           // ushort index in frag order

  // B frag base units for this wave (ni=0..3): n = w*64 + ni*16
  int ub[4];
#pragma unroll
  for (int ni = 0; ni < 4; ++ni) {
    int q = 4 * w + ni;
    ub[ni] = (q >> 3) * 512 + (q & 7) * 64;
  }

  f32x4 acc[4][4];
#pragma unroll
  for (int mi = 0; mi < 4; ++mi)
#pragma unroll
    for (int ni = 0; ni < 4; ++ni) acc[mi][ni] = (f32x4){0.f, 0.f, 0.f, 0.f};

  // ---- prologue: stage B(0) via DMA + x(0) via regs ----
#pragma unroll
  for (int j = 0; j < 4; ++j) {
    const int cu = j * 512 + w * 64;        // chunk unit base (wave-uniform)
    GLOAD_LDS16(Wt + (size_t)(cu + lane) * 8, &bs[0][cu * 8]);
  }
  {
    float4 v = *(const float4*)xsrc;
    uint2 pk;
    pk.x = (unsigned)f2bf(v.x) | ((unsigned)f2bf(v.y) << 16);
    pk.y = (unsigned)f2bf(v.z) | ((unsigned)f2bf(v.w) << 16);
    *(uint2*)(&xsh[0][xu8]) = pk;
  }
  __syncthreads();

  // ---- main loop ----
#pragma unroll 1
  for (int kc = 0; kc < 16; ++kc) {
    const int cur = kc & 1, nxt = cur ^ 1;
    float4 nx;
    if (kc < 15) {
      // issue next B tile DMA (lands during MFMA below)
      const unsigned short* wsrc = Wt + (size_t)(kc + 1) * 16384;
#pragma unroll
      for (int j = 0; j < 4; ++j) {
        const int cu = j * 512 + w * 64;
        GLOAD_LDS16(wsrc + (size_t)(cu + lane) * 8, &bs[nxt][cu * 8]);
      }
      nx = *(const float4*)(xsrc + (kc + 1) * 32);
    }
    // fragment reads (lane-linear, conflict-free)
    bf16x8 af[4], bf[4];
#pragma unroll
    for (int mi = 0; mi < 4; ++mi)
      af[mi] = *(const bf16x8*)(&xsh[cur][(mi * 64 + lane) * 8]);
#pragma unroll
    for (int ni = 0; ni < 4; ++ni)
      bf[ni] = *(const bf16x8*)(&bs[cur][(ub[ni] + lane) * 8]);
    __builtin_amdgcn_s_setprio(1);
#pragma unroll
    for (int mi = 0; mi < 4; ++mi)
#pragma unroll
      for (int ni = 0; ni < 4; ++ni)
        acc[mi][ni] = __builtin_amdgcn_mfma_f32_16x16x32_bf16(
            af[mi], bf[ni], acc[mi][ni], 0, 0, 0);
    __builtin_amdgcn_s_setprio(0);
    if (kc < 15) {
      uint2 pk;
      pk.x = (unsigned)f2bf(nx.x) | ((unsigned)f2bf(nx.y) << 16);
      pk.y = (unsigned)f2bf(nx.z) | ((unsigned)f2bf(nx.w) << 16);
      *(uint2*)(&xsh[nxt][xu8]) = pk;
    }
    __syncthreads();   // drains B-DMA (vmcnt) + LDS writes for next iter
  }

  // ---- epilogue: pre += base; tanh; dot with W2 slice; reduce ----
  float w2v[4];
#pragma unroll
  for (int ni = 0; ni < 4; ++ni) w2v[ni] = W2[w * 64 + ni * 16 + l15];
  float lsum[4][4];
#pragma unroll
  for (int mi = 0; mi < 4; ++mi) {
#pragma unroll
    for (int rg = 0; rg < 4; ++rg) {
      int m = m0 + mi * 16 + lg * 4 + rg;
      int bb = m & 31;
      const float* brow = base + (size_t)bb * 512 + w * 64;
      float s = 0.f;
#pragma unroll
      for (int ni = 0; ni < 4; ++ni) {
        float pre = acc[mi][ni][rg] + brow[ni * 16 + l15];
        s = fmaf(tanh_fast(pre), w2v[ni], s);
      }
      lsum[mi][rg] = s;
    }
  }
  // reduce 16-col partials within lane groups, then across the 8 waves
  float (*lred)[64] = (float (*)[64])xsh;   // 2 KB scratch (xsh dead)
#pragma unroll
  for (int mi = 0; mi < 4; ++mi)
#pragma unroll
    for (int rg = 0; rg < 4; ++rg) {
      float v = lsum[mi][rg];
      v += __shfl_xor(v, 1); v += __shfl_xor(v, 2);
      v += __shfl_xor(v, 4); v += __shfl_xor(v, 8);
      if (l15 == 0) lred[w][mi * 16 + lg * 4 + rg] = v;
    }
  __syncthreads();
  if (tid < 64) {
    float v = 0.f;
#pragma unroll
    for (int wq = 0; wq < 8; ++wq) v += lred[wq][tid];
    logit[m0 + tid] = v;
  }
}

// ---------------- kernel 4: masked softmax over L per b ----------------
__global__ __launch_bounds__(256) void k_softmax(const float* __restrict__ logit,
                                                 const int* __restrict__ mask,
                                                 float* __restrict__ p) {
  const int b = blockIdx.x, tid = threadIdx.x;
  float lv[8]; float mx = -3.0e38f;
#pragma unroll
  for (int i = 0; i < 8; ++i) {
    int idx = (tid + i * 256) * 32 + b;
    float v = (mask[idx] != 0) ? logit[idx] : -1.0e10f;
    lv[i] = v; mx = fmaxf(mx, v);
  }
  __shared__ float red[8];
  for (int d = 1; d < 64; d <<= 1) mx = fmaxf(mx, __shfl_xor(mx, d));
  if ((tid & 63) == 0) red[tid >> 6] = mx;
  __syncthreads();
  mx = fmaxf(fmaxf(red[0], red[1]), fmaxf(red[2], red[3]));
  float s = 0.f;
#pragma unroll
  for (int i = 0; i < 8; ++i) { lv[i] = __expf(lv[i] - mx); s += lv[i]; }
  for (int d = 1; d < 64; d <<= 1) s += __shfl_xor(s, d);
  __syncthreads();
  if ((tid & 63) == 0) red[4 + (tid >> 6)] = s;
  __syncthreads();
  s = (red[4] + red[5]) + (red[6] + red[7]);
  float inv = 1.f / s;
#pragma unroll
  for (int i = 0; i < 8; ++i) {
    int idx = (tid + i * 256) * 32 + b;
    p[idx] = lv[i] * inv;
  }
}

// ------- kernel 5: partial ctx: part[b][ch][e] = sum_{l in ch} p*x ---------
__global__ __launch_bounds__(128) void k_ctx(const float* __restrict__ x,
                                             const float* __restrict__ p,
                                             float* __restrict__ part) {
  const int blk = blockIdx.x;            // 1024 = 32 b * 32 chunks
  const int b = blk >> 5, ch = blk & 31;
  const int tid = threadIdx.x;           // 128 threads, float4 each
  __shared__ float ps[64];
  const int l0 = ch * 64;
  if (tid < 64) ps[tid] = p[(l0 + tid) * 32 + b];
  __syncthreads();
  const float* xb = x + ((size_t)l0 * 32 + b) * 512 + tid * 4;
  float ax = 0.f, ay = 0.f, az = 0.f, aw = 0.f;
#pragma unroll 4
  for (int i = 0; i < 64; ++i) {
    float4 v = *(const float4*)(xb + (size_t)i * 32 * 512);
    float pv = ps[i];
    ax = fmaf(pv, v.x, ax); ay = fmaf(pv, v.y, ay);
    az = fmaf(pv, v.z, az); aw = fmaf(pv, v.w, aw);
  }
  float4 r; r.x = ax; r.y = ay; r.z = az; r.w = aw;
  *(float4*)(part + (size_t)blk * 512 + tid * 4) = r;
}

// ------- kernel 6: reduce partials -> ctx, concat action_feature -----------
__global__ __launch_bounds__(256) void k_final(const float* __restrict__ part,
                                               const float* __restrict__ af,
                                               float* __restrict__ out) {
  const int b = blockIdx.x, tid = threadIdx.x;
  float ax = 0.f, ay = 0.f;
#pragma unroll
  for (int ch = 0; ch < 32; ++ch) {
    float2 v = *(const float2*)(part + ((size_t)(b * 32 + ch) * 512) + tid * 2);
    ax += v.x; ay += v.y;
  }
  float2 r; r.x = ax; r.y = ay;
  *(float2*)(out + (size_t)b * 1024 + tid * 2) = r;
  float2 a = *(const float2*)(af + (size_t)b * 512 + tid * 2);
  *(float2*)(out + (size_t)b * 1024 + 512 + tid * 2) = a;
}

extern "C" void kernel_launch(void* const* d_in, const int* in_sizes, int n_in,
                              void* d_out, int out_size, void* d_ws, size_t ws_size,
                              hipStream_t stream) {
  const float* x      = (const float*)d_in[0];
  const int*   mask   = (const int*)d_in[1];
  const float* af     = (const float*)d_in[2];
  const float* hidden = (const float*)d_in[3];
  // d_in[4] = state (unused by reference output)
  const float* W1     = (const float*)d_in[5];
  const float* b1     = (const float*)d_in[6];
  const float* W2     = (const float*)d_in[7];
  // d_in[8] = b2 (softmax-invariant, skipped)
  float* out = (float*)d_out;
  char* ws = (char*)d_ws;
  float*          base  = (float*)(ws + OFF_BASE);
  unsigned short* Wt    = (unsigned short*)(ws + OFF_WT);
  float*          logit = (float*)(ws + OFF_LOGIT);
  float*          p     = (float*)(ws + OFF_P);
  float*          part  = (float*)(ws + OFF_PART);

  k_base   <<<32,   256, 0, stream>>>(hidden, W1, b1, base);
  k_prep_wt<<<16,   256, 0, stream>>>(W1, Wt);
  k_logits <<<1024, 512, 0, stream>>>(x, Wt, base, W2, logit);
  k_softmax<<<32,   256, 0, stream>>>(logit, mask, p);
  k_ctx    <<<1024, 128, 0, stream>>>(x, p, part);
  k_final  <<<32,   256, 0, stream>>>(part, af, out);
}

// Round 12
// 119.873 us; speedup vs baseline: 1.0069x; 1.0069x over previous
//
#include <hip/hip_runtime.h>
#include <hip/hip_bf16.h>
#include <stdint.h>

// Problem constants (from reference setup_inputs)
#define L_DIM 2048
#define B_DIM 32
#define E_DIM 512
#define HID_DIM 512
#define M_DIM (L_DIM * B_DIM)   // 65536 rows, row m = l*32 + b

typedef float f32x4 __attribute__((ext_vector_type(4)));
typedef short bf16x8 __attribute__((ext_vector_type(8)));

// ws layout (bytes); requires ws_size >= 3211264 (~3.1 MB) — unchanged (known OK)
#define OFF_BASE  0         // 32*512 f32          = 65536
#define OFF_WT    65536     // 512*512 bf16        = 524288  -> 589824
#define OFF_LOGIT 589824    // 65536 f32           = 262144  -> 851968
#define OFF_P     851968    // 65536 f32           = 262144  -> 1114112
#define OFF_PART  1114112   // 32*32*512 f32       = 2097152 -> 3211264

__device__ __forceinline__ unsigned short f2bf(float f) {
  unsigned int u = __float_as_uint(f);
  u = (u + 0x7FFFu + ((u >> 16) & 1u)) >> 16;   // RNE
  return (unsigned short)u;
}

__device__ __forceinline__ float tanh_fast(float x) {
  float xc = fminf(fmaxf(x, -15.f), 15.f);
  float e = __expf(2.f * xc);
  return (e - 1.f) * __builtin_amdgcn_rcpf(e + 1.f);
}

// pack 8 fp32 (two f32x4) -> 8 bf16 in a uint4
__device__ __forceinline__ uint4 pack8v(const f32x4& a, const f32x4& b) {
  uint4 r;
  r.x = (unsigned)f2bf(a[0]) | ((unsigned)f2bf(a[1]) << 16);
  r.y = (unsigned)f2bf(a[2]) | ((unsigned)f2bf(a[3]) << 16);
  r.z = (unsigned)f2bf(b[0]) | ((unsigned)f2bf(b[1]) << 16);
  r.w = (unsigned)f2bf(b[2]) | ((unsigned)f2bf(b[3]) << 16);
  return r;
}

// non-temporal load (nt flag: no L2 allocation -> x stream can't evict Wt)
#define NT_LOAD(p) __builtin_nontemporal_load(p)

// async global->LDS DMA, 16 B per lane (m97-verified path)
#define GLOAD_LDS16(gsrc, ldst) \
  __builtin_amdgcn_global_load_lds( \
      (const __attribute__((address_space(1))) void*)(gsrc), \
      (__attribute__((address_space(3))) void*)(ldst), 16, 0, 0)

// ---------------- kernel 1: base[b][h] = hidden[b]@W1_h + b1 ----------------
__global__ __launch_bounds__(256) void k_base(const float* __restrict__ hidden,
                                              const float* __restrict__ W1,
                                              const float* __restrict__ b1,
                                              float* __restrict__ base) {
  const int b = blockIdx.x;
  const int tid = threadIdx.x;
  __shared__ float hs[HID_DIM];
  {
    float2 v = *(const float2*)(hidden + (size_t)b * 512 + tid * 2);
    hs[tid * 2] = v.x; hs[tid * 2 + 1] = v.y;
  }
  __syncthreads();
  const int h = tid * 2;
  float2 b1v = *(const float2*)(b1 + h);
  float ax = b1v.x, ay = b1v.y;
#pragma unroll 8
  for (int e = 0; e < 512; ++e) {
    float2 w = *(const float2*)(W1 + (size_t)e * 512 + h);
    float hv = hs[e];
    ax = fmaf(hv, w.x, ax);
    ay = fmaf(hv, w.y, ay);
  }
  float2 r; r.x = ax; r.y = ay;
  *(float2*)(base + (size_t)b * 512 + h) = r;
}

// ------- kernel 2: pre-permute W1_e into MFMA-fragment order ------
// Wt unit index (16B units, 2048 per kc): u = (n>>7)*512 + ((n>>4)&7)*64 + lg*16 + (n&15)
// content: 8 bf16 of W1_e[k = kc*32 + lg*8 + j][n]
__global__ __launch_bounds__(256) void k_prep_wt(const float* __restrict__ W1,
                                                 unsigned short* __restrict__ Wt) {
  const int kc = blockIdx.x;   // 16 blocks
  const int tid = threadIdx.x;
  __shared__ unsigned short sh[32][516];   // +4 pad to spread strided col reads
#pragma unroll
  for (int i = 0; i < 16; ++i) {
    int f4 = i * 256 + tid;                 // 4096 float4 total
    int r = f4 >> 7;                        // 0..31
    int c = (f4 & 127) * 4;                 // 0..508
    float4 v = *(const float4*)(W1 + (size_t)(512 + kc * 32 + r) * 512 + c);
    sh[r][c + 0] = f2bf(v.x); sh[r][c + 1] = f2bf(v.y);
    sh[r][c + 2] = f2bf(v.z); sh[r][c + 3] = f2bf(v.w);
  }
  __syncthreads();
#pragma unroll
  for (int i = 0; i < 8; ++i) {
    int u = i * 256 + tid;                  // 0..2047
    int n = ((u >> 9) << 7) + (((u >> 6) & 7) << 4) + (u & 15);
    int k0 = ((u >> 4) & 3) << 3;
    alignas(16) unsigned short tmp[8];
#pragma unroll
    for (int j = 0; j < 8; ++j) tmp[j] = sh[k0 + j][n];
    *(uint4*)(Wt + ((size_t)kc * 2048 + u) * 8) = *(const uint4*)tmp;
  }
}

// ------- kernel 3: fused GEMM + tanh + W2 reduce -> logit[m] ---------------
// R11 structure + ONE mechanism change: x loads are NON-TEMPORAL so the
// 134 MB fp32 x stream does not allocate in L2 and cannot evict the 512 KB
// Wt working set -> the B-stream (512 MB of re-reads) is served at L2 BW
// instead of L3/HBM. Loop order: x NT-load FIRST, then B-DMAs, so the f2bf
// wait is vmcnt(4) (B-DMAs stay in flight through the MFMA cluster).
__global__ __launch_bounds__(512, 4) void k_logits(
    const float* __restrict__ x, const unsigned short* __restrict__ Wt,
    const float* __restrict__ base, const float* __restrict__ W2,
    float* __restrict__ logit) {
  __shared__ unsigned short bs[2][16384];   // B tile: 2048 units x 16B (32 KB/buf)
  __shared__ unsigned short xsh[2][2048];   // x tile: 256 units x 16B (4 KB/buf)
  const int tid = threadIdx.x;
  const int m0 = blockIdx.x * 64;
  const int w = tid >> 6, lane = tid & 63;  // w = N-slice 0..7 (cols w*64..+63)
  const int lg = lane >> 4, l15 = lane & 15;

  // x staging map: row r = tid>>3 (0..63), seg = tid&7 (4 floats each)
  const int xr = tid >> 3, xseg = tid & 7;
  const float* xsrc = x + (size_t)(m0 + xr) * 512 + xseg * 4;
  const int xu8 = (((xr >> 4) << 6) + ((xseg >> 1) << 4) + (xr & 15)) * 8 +
                  (xseg & 1) * 4;           // ushort index in frag order

  // B frag base units for this wave (ni=0..3): n = w*64 + ni*16
  int ub[4];
#pragma unroll
  for (int ni = 0; ni < 4; ++ni) {
    int q = 4 * w + ni;
    ub[ni] = (q >> 3) * 512 + (q & 7) * 64;
  }

  f32x4 acc[4][4];
#pragma unroll
  for (int mi = 0; mi < 4; ++mi)
#pragma unroll
    for (int ni = 0; ni < 4; ++ni) acc[mi][ni] = (f32x4){0.f, 0.f, 0.f, 0.f};

  // ---- prologue: stage x(0) (NT) + B(0) via DMA ----
  {
    f32x4 va = NT_LOAD((const f32x4*)xsrc);
#pragma unroll
    for (int j = 0; j < 4; ++j) {
      const int cu = j * 512 + w * 64;      // chunk unit base (wave-uniform)
      GLOAD_LDS16(Wt + (size_t)(cu + lane) * 8, &bs[0][cu * 8]);
    }
    uint2 pk;
    pk.x = (unsigned)f2bf(va[0]) | ((unsigned)f2bf(va[1]) << 16);
    pk.y = (unsigned)f2bf(va[2]) | ((unsigned)f2bf(va[3]) << 16);
    *(uint2*)(&xsh[0][xu8]) = pk;
  }
  __syncthreads();

  // ---- main loop ----
#pragma unroll 1
  for (int kc = 0; kc < 16; ++kc) {
    const int cur = kc & 1, nxt = cur ^ 1;
    f32x4 nx;
    if (kc < 15) {
      // x NT-load FIRST (oldest in vmem queue), then next B tile DMA
      nx = NT_LOAD((const f32x4*)(xsrc + (kc + 1) * 32));
      const unsigned short* wsrc = Wt + (size_t)(kc + 1) * 16384;
#pragma unroll
      for (int j = 0; j < 4; ++j) {
        const int cu = j * 512 + w * 64;
        GLOAD_LDS16(wsrc + (size_t)(cu + lane) * 8, &bs[nxt][cu * 8]);
      }
    }
    // fragment reads (lane-linear, conflict-free)
    bf16x8 af[4], bf[4];
#pragma unroll
    for (int mi = 0; mi < 4; ++mi)
      af[mi] = *(const bf16x8*)(&xsh[cur][(mi * 64 + lane) * 8]);
#pragma unroll
    for (int ni = 0; ni < 4; ++ni)
      bf[ni] = *(const bf16x8*)(&bs[cur][(ub[ni] + lane) * 8]);
#pragma unroll
    for (int mi = 0; mi < 4; ++mi)
#pragma unroll
      for (int ni = 0; ni < 4; ++ni)
        acc[mi][ni] = __builtin_amdgcn_mfma_f32_16x16x32_bf16(
            af[mi], bf[ni], acc[mi][ni], 0, 0, 0);
    if (kc < 15) {
      // f2bf(nx) waits only on the x load (4 newer B-DMAs stay in flight)
      uint2 pk;
      pk.x = (unsigned)f2bf(nx[0]) | ((unsigned)f2bf(nx[1]) << 16);
      pk.y = (unsigned)f2bf(nx[2]) | ((unsigned)f2bf(nx[3]) << 16);
      *(uint2*)(&xsh[nxt][xu8]) = pk;
    }
    __syncthreads();   // drains B-DMA (vmcnt) + LDS writes for next iter
  }

  // ---- epilogue: pre += base; tanh; dot with W2 slice; reduce ----
  float w2v[4];
#pragma unroll
  for (int ni = 0; ni < 4; ++ni) w2v[ni] = W2[w * 64 + ni * 16 + l15];
  float lsum[4][4];
#pragma unroll
  for (int mi = 0; mi < 4; ++mi) {
#pragma unroll
    for (int rg = 0; rg < 4; ++rg) {
      int m = m0 + mi * 16 + lg * 4 + rg;
      int bb = m & 31;
      const float* brow = base + (size_t)bb * 512 + w * 64;
      float s = 0.f;
#pragma unroll
      for (int ni = 0; ni < 4; ++ni) {
        float pre = acc[mi][ni][rg] + brow[ni * 16 + l15];
        s = fmaf(tanh_fast(pre), w2v[ni], s);
      }
      lsum[mi][rg] = s;
    }
  }
  // reduce 16-col partials within lane groups, then across the 8 waves
  float (*lred)[64] = (float (*)[64])xsh;   // 2 KB scratch (xsh dead)
#pragma unroll
  for (int mi = 0; mi < 4; ++mi)
#pragma unroll
    for (int rg = 0; rg < 4; ++rg) {
      float v = lsum[mi][rg];
      v += __shfl_xor(v, 1); v += __shfl_xor(v, 2);
      v += __shfl_xor(v, 4); v += __shfl_xor(v, 8);
      if (l15 == 0) lred[w][mi * 16 + lg * 4 + rg] = v;
    }
  __syncthreads();
  if (tid < 64) {
    float v = 0.f;
#pragma unroll
    for (int wq = 0; wq < 8; ++wq) v += lred[wq][tid];
    logit[m0 + tid] = v;
  }
}

// ---------------- kernel 4: masked softmax over L per b ----------------
__global__ __launch_bounds__(256) void k_softmax(const float* __restrict__ logit,
                                                 const int* __restrict__ mask,
                                                 float* __restrict__ p) {
  const int b = blockIdx.x, tid = threadIdx.x;
  float lv[8]; float mx = -3.0e38f;
#pragma unroll
  for (int i = 0; i < 8; ++i) {
    int idx = (tid + i * 256) * 32 + b;
    float v = (mask[idx] != 0) ? logit[idx] : -1.0e10f;
    lv[i] = v; mx = fmaxf(mx, v);
  }
  __shared__ float red[8];
  for (int d = 1; d < 64; d <<= 1) mx = fmaxf(mx, __shfl_xor(mx, d));
  if ((tid & 63) == 0) red[tid >> 6] = mx;
  __syncthreads();
  mx = fmaxf(fmaxf(red[0], red[1]), fmaxf(red[2], red[3]));
  float s = 0.f;
#pragma unroll
  for (int i = 0; i < 8; ++i) { lv[i] = __expf(lv[i] - mx); s += lv[i]; }
  for (int d = 1; d < 64; d <<= 1) s += __shfl_xor(s, d);
  __syncthreads();
  if ((tid & 63) == 0) red[4 + (tid >> 6)] = s;
  __syncthreads();
  s = (red[4] + red[5]) + (red[6] + red[7]);
  float inv = 1.f / s;
#pragma unroll
  for (int i = 0; i < 8; ++i) {
    int idx = (tid + i * 256) * 32 + b;
    p[idx] = lv[i] * inv;
  }
}

// ------- kernel 5: partial ctx: part[b][ch][e] = sum_{l in ch} p*x ---------
__global__ __launch_bounds__(128) void k_ctx(const float* __restrict__ x,
                                             const float* __restrict__ p,
                                             float* __restrict__ part) {
  const int blk = blockIdx.x;            // 1024 = 32 b * 32 chunks
  const int b = blk >> 5, ch = blk & 31;
  const int tid = threadIdx.x;           // 128 threads, float4 each
  __shared__ float ps[64];
  const int l0 = ch * 64;
  if (tid < 64) ps[tid] = p[(l0 + tid) * 32 + b];
  __syncthreads();
  const float* xb = x + ((size_t)l0 * 32 + b) * 512 + tid * 4;
  float ax = 0.f, ay = 0.f, az = 0.f, aw = 0.f;
#pragma unroll 4
  for (int i = 0; i < 64; ++i) {
    f32x4 v = NT_LOAD((const f32x4*)(xb + (size_t)i * 32 * 512));
    float pv = ps[i];
    ax = fmaf(pv, v[0], ax); ay = fmaf(pv, v[1], ay);
    az = fmaf(pv, v[2], az); aw = fmaf(pv, v[3], aw);
  }
  float4 r; r.x = ax; r.y = ay; r.z = az; r.w = aw;
  *(float4*)(part + (size_t)blk * 512 + tid * 4) = r;
}

// ------- kernel 6: reduce partials -> ctx, concat action_feature -----------
__global__ __launch_bounds__(256) void k_final(const float* __restrict__ part,
                                               const float* __restrict__ af,
                                               float* __restrict__ out) {
  const int b = blockIdx.x, tid = threadIdx.x;
  float ax = 0.f, ay = 0.f;
#pragma unroll
  for (int ch = 0; ch < 32; ++ch) {
    float2 v = *(const float2*)(part + ((size_t)(b * 32 + ch) * 512) + tid * 2);
    ax += v.x; ay += v.y;
  }
  float2 r; r.x = ax; r.y = ay;
  *(float2*)(out + (size_t)b * 1024 + tid * 2) = r;
  float2 a = *(const float2*)(af + (size_t)b * 512 + tid * 2);
  *(float2*)(out + (size_t)b * 1024 + 512 + tid * 2) = a;
}

extern "C" void kernel_launch(void* const* d_in, const int* in_sizes, int n_in,
                              void* d_out, int out_size, void* d_ws, size_t ws_size,
                              hipStream_t stream) {
  const float* x      = (const float*)d_in[0];
  const int*   mask   = (const int*)d_in[1];
  const float* af     = (const float*)d_in[2];
  const float* hidden = (const float*)d_in[3];
  // d_in[4] = state (unused by reference output)
  const float* W1     = (const float*)d_in[5];
  const float* b1     = (const float*)d_in[6];
  const float* W2     = (const float*)d_in[7];
  // d_in[8] = b2 (softmax-invariant, skipped)
  float* out = (float*)d_out;
  char* ws = (char*)d_ws;
  float*          base  = (float*)(ws + OFF_BASE);
  unsigned short* Wt    = (unsigned short*)(ws + OFF_WT);
  float*          logit = (float*)(ws + OFF_LOGIT);
  float*          p     = (float*)(ws + OFF_P);
  float*          part  = (float*)(ws + OFF_PART);

  k_base   <<<32,   256, 0, stream>>>(hidden, W1, b1, base);
  k_prep_wt<<<16,   256, 0, stream>>>(W1, Wt);
  k_logits <<<1024, 512, 0, stream>>>(x, Wt, base, W2, logit);
  k_softmax<<<32,   256, 0, stream>>>(logit, mask, p);
  k_ctx    <<<1024, 128, 0, stream>>>(x, p, part);
  k_final  <<<32,   256, 0, stream>>>(part, af, out);
}